// Round 2
// baseline (557.743 us; speedup 1.0000x reference)
//
#include <hip/hip_runtime.h>
#include <math.h>

#define NEG_SLOPE 0.2f

// K1: h = x @ W   [N,128]x[128,64], plus a_src = h@att_src, a_dst = h@att_dst
__global__ __launch_bounds__(256) void k_gemm_att(
    const float* __restrict__ x, const float* __restrict__ W,
    const float* __restrict__ att_src, const float* __restrict__ att_dst,
    float* __restrict__ h, float* __restrict__ a_src, float* __restrict__ a_dst,
    int N)
{
    __shared__ float Ws[128 * 64];  // 32 KiB
    for (int i = threadIdx.x; i < 128 * 64 / 4; i += 256)
        ((float4*)Ws)[i] = ((const float4*)W)[i];
    __syncthreads();

    const int lane = threadIdx.x & 63;
    const int wid  = blockIdx.x * (blockDim.x >> 6) + (threadIdx.x >> 6);
    const int nw   = gridDim.x * (blockDim.x >> 6);
    const float as = att_src[lane];
    const float ad = att_dst[lane];

    for (int n = wid; n < N; n += nw) {
        // lane l holds x[n][2l], x[n][2l+1]
        float2 xv = ((const float2*)(x + (size_t)n * 128))[lane];
        float acc = 0.f;
        #pragma unroll
        for (int kk = 0; kk < 64; ++kk) {
            float a0 = __shfl(xv.x, kk);   // broadcast x[n][2kk]
            float a1 = __shfl(xv.y, kk);   // broadcast x[n][2kk+1]
            acc = fmaf(a0, Ws[(2 * kk) * 64 + lane], acc);
            acc = fmaf(a1, Ws[(2 * kk + 1) * 64 + lane], acc);
        }
        h[(size_t)n * 64 + lane] = acc;
        float ps = acc * as, pd = acc * ad;
        #pragma unroll
        for (int off = 32; off >= 1; off >>= 1) {
            ps += __shfl_xor(ps, off);
            pd += __shfl_xor(pd, off);
        }
        if (lane == 0) { a_src[n] = ps; a_dst[n] = pd; }
    }
}

// K2: one pass over all E+N messages (self loops appended).
// Each wave takes 64 messages: per-lane scalar phase (e, exp, denom atomic),
// then 64 broadcast iterations scattering h[src]*ex into accum[dst].
__global__ __launch_bounds__(256) void k_edges(
    const int* __restrict__ src_idx, const int* __restrict__ dst_idx,
    const float* __restrict__ a_src, const float* __restrict__ a_dst,
    const float* __restrict__ h,
    float* __restrict__ denom, float* __restrict__ accum,
    int E, int M)
{
    const int lane = threadIdx.x & 63;
    const long wid = (long)blockIdx.x * (blockDim.x >> 6) + (threadIdx.x >> 6);
    const long nw  = (long)gridDim.x * (blockDim.x >> 6);

    for (long base = wid * 64; base < M; base += nw * 64) {
        long m = base + lane;
        int s = 0, d = 0;
        float ex = 0.f;
        if (m < M) {
            if (m < E) { s = src_idx[m]; d = dst_idx[m]; }
            else       { s = d = (int)(m - E); }          // self loop
            float e = a_src[s] + a_dst[d];
            e  = e > 0.f ? e : NEG_SLOPE * e;
            ex = __expf(e);
            atomicAdd(denom + d, ex);
        }
        const int cnt = (int)((M - base) < 64 ? (M - base) : 64);
        for (int j = 0; j < cnt; ++j) {
            int   sj  = __shfl(s, j);
            int   dj  = __shfl(d, j);
            float exj = __shfl(ex, j);
            float hv  = h[(size_t)sj * 64 + lane];        // 256B coalesced row
            atomicAdd(accum + (size_t)dj * 64 + lane, hv * exj);
        }
    }
}

// K3: out = elu(accum/denom + bias), in place on d_out
__global__ __launch_bounds__(256) void k_final(
    float* __restrict__ accum, const float* __restrict__ denom,
    const float* __restrict__ bias, int N)
{
    const long total = (long)N * 64;
    const long stride = (long)gridDim.x * 256;
    for (long i = (long)blockIdx.x * 256 + threadIdx.x; i < total; i += stride) {
        int n = (int)(i >> 6), d = (int)(i & 63);
        float v = accum[i] / denom[n] + bias[d];
        accum[i] = v > 0.f ? v : expm1f(v);
    }
}

extern "C" void kernel_launch(void* const* d_in, const int* in_sizes, int n_in,
                              void* d_out, int out_size, void* d_ws, size_t ws_size,
                              hipStream_t stream)
{
    const float* x       = (const float*)d_in[0];
    const float* W       = (const float*)d_in[1];
    const float* att_src = (const float*)d_in[2];
    const float* att_dst = (const float*)d_in[3];
    const float* bias    = (const float*)d_in[4];
    const int*   eidx    = (const int*)d_in[5];   // [2,E] int (harness converts integers to int32)

    const int N = in_sizes[0] / 128;
    const int E = in_sizes[5] / 2;
    const int M = E + N;

    float* out = (float*)d_out;                   // also the accumulator
    float* h      = (float*)d_ws;                 // N*64
    float* a_src  = h + (size_t)N * 64;           // N
    float* a_dst  = a_src + N;                    // N
    float* denom  = a_dst + N;                    // N

    hipMemsetAsync(out,   0, (size_t)N * 64 * sizeof(float), stream);
    hipMemsetAsync(denom, 0, (size_t)N * sizeof(float), stream);

    k_gemm_att<<<1024, 256, 0, stream>>>(x, W, att_src, att_dst, h, a_src, a_dst, N);

    const int blocks2 = (M + 255) / 256;          // 4 waves/block, 64 msgs/wave
    k_edges<<<blocks2, 256, 0, stream>>>(eidx, eidx + E, a_src, a_dst, h, denom, out, E, M);

    k_final<<<4096, 256, 0, stream>>>(out, denom, bias, N);
}